// Round 6
// baseline (746.278 us; speedup 1.0000x reference)
//
#include <hip/hip_runtime.h>
#include <stdint.h>

#define NN   8192
#define DIN  256
#define FF   128
#define NF   (NN*FF)          // 1048576
#define SLOPE 0.2f
#define EPSI  1e-5f
#define LOG2E 1.4426950408889634f

typedef short bf16x8 __attribute__((ext_vector_type(8)));
typedef float f32x4 __attribute__((ext_vector_type(4)));
typedef float vf4 __attribute__((ext_vector_type(4)));   // ext-vector float4 (nontemporal-legal)

// ---- workspace layout (float offsets) ----
#define OFF_BM     0                       // bitmask [N][256] u32 (8 MB)
#define OFF_RESID  (2*NF)                  // [N][F] f32
#define OFF_AVEC   (3*NF)                  // [4][DIN] f32: Wa_src(h0,h1), Wa_tgt(h0,h1)
#define OFF_SS     (4*NF)                  // s_src [2][N] (unscaled)
#define OFF_ST     (OFF_SS + 2*NN)         // s_tgt [2][N] (unscaled)
#define OFF_CSUM   (OFF_ST + 2*NN)         // (unused, kept for layout stability)
#define OFF_STATS  (OFF_CSUM + 2*NN)       // S, SS (padded to 16)
#define OFF_NTAB   (OFF_STATS + 16)        // float4[N] = {st0*log2e, st1*log2e, rcp0, rcp1}
#define OFF_VALS   (OFF_NTAB + 4*NN)       // [N][F] f32
#define OFF_WT     (OFF_VALS + NF)         // W_res^T [DIN][F]
#define OFF_PT2    (OFF_WT + DIN*FF)       // packedT2: [N/32][2][128][16] u32 (4 MB)
#define OFF_VPART  (OFF_PT2 + NF)          // vpart: [8][N][F] f32 (32 MB)

__device__ __forceinline__ float lrelu(float x) { return x >= 0.f ? x : SLOPE * x; }
__device__ __forceinline__ float exp2fast(float x) { return __builtin_amdgcn_exp2f(x); }

__device__ __forceinline__ uint32_t bfpack(float a, float b) {
  uint32_t ua = __float_as_uint(a); ua += 0x7fffu + ((ua >> 16) & 1u);
  uint32_t ub = __float_as_uint(b); ub += 0x7fffu + ((ub >> 16) & 1u);
  return (ua >> 16) | (ub & 0xffff0000u);
}
__device__ __forceinline__ uint16_t bf16c(float a) {
  uint32_t u = __float_as_uint(a); u += 0x7fffu + ((u >> 16) & 1u);
  return (uint16_t)(u >> 16);
}

// ---- K_copy: PURE stream. mask -> out copy (vf4, contiguous sweeps) + bitmask emit.
// Block = 4 full rows (4 x 32 KB). Zero LDS, no exp, no ss/st dep. 2048 blocks. ----
__global__ __launch_bounds__(256) void k_copy(const float* __restrict__ mask, float* __restrict__ maskout,
                                              uint32_t* __restrict__ bitmask) {
  const int t = threadIdx.x;
  const int L = t & 63, wv = t >> 6;
  const int m0 = blockIdx.x * 4;
#pragma unroll
  for (int j = 0; j < 4; ++j) {
    const size_t rowoff = (size_t)(m0 + j) * NN;
    vf4 v[8];
#pragma unroll
    for (int s = 0; s < 8; ++s)
      v[s] = __builtin_nontemporal_load((const vf4*)&mask[rowoff + s * 1024 + t * 4]);
#pragma unroll
    for (int s = 0; s < 8; ++s) {
      __builtin_nontemporal_store(v[s], (vf4*)&maskout[rowoff + s * 1024 + t * 4]);
      uint32_t nib = (v[s].x > -0.5e9f ? 1u : 0u) | (v[s].y > -0.5e9f ? 2u : 0u) |
                     (v[s].z > -0.5e9f ? 4u : 0u) | (v[s].w > -0.5e9f ? 8u : 0u);
      uint32_t w = nib << (4 * (L & 7));
      w |= __shfl_xor((int)w, 1); w |= __shfl_xor((int)w, 2); w |= __shfl_xor((int)w, 4);
      if ((L & 7) == 0)
        bitmask[(m0 + j) * 256 + s * 32 + wv * 8 + (L >> 3)] = w;
    }
  }
}

// ---- K_prep: W_res transpose (blocks 0..127) + avec = {W_h a_src, W_h a_tgt} (blocks 128..131) ----
__global__ __launch_bounds__(256) void k_prep(const float* __restrict__ wres, float* __restrict__ wtr,
                                              const float* __restrict__ W, const float* __restrict__ a_src,
                                              const float* __restrict__ a_tgt, float* __restrict__ avec) {
  const int b = blockIdx.x;
  if (b < 128) {
    int i = b * 256 + threadIdx.x;
    int d = i >> 7, f = i & 127;
    wtr[i] = wres[f * DIN + d];
  } else {
    int j = b - 128;                       // 0: ss_h0, 1: ss_h1, 2: st_h0, 3: st_h1
    int h = j & 1, tg = j >> 1;
    const float* a = (tg ? a_tgt : a_src) + h * FF;
    const float* Wp = W + ((size_t)h * DIN + threadIdx.x) * FF;
    float s = 0.f;
#pragma unroll 8
    for (int f = 0; f < FF; ++f) s += Wp[f] * a[f];
    avec[j * DIN + threadIdx.x] = s;
  }
}

// ---- K_ss: ss/st = x . avec  (factored: (xW).a == x.(Wa)) ----
__global__ __launch_bounds__(256) void k_ss(const float* __restrict__ x, const float* __restrict__ avec,
                                            float* __restrict__ ss, float* __restrict__ st) {
  const int lane = threadIdx.x & 63, wid = threadIdx.x >> 6;
  const int n = blockIdx.x * 4 + wid;
  float4 xv = *(const float4*)&x[n * DIN + 4 * lane];
  float4 c0 = *(const float4*)&avec[0 * DIN + 4 * lane];
  float4 c1 = *(const float4*)&avec[1 * DIN + 4 * lane];
  float4 c2 = *(const float4*)&avec[2 * DIN + 4 * lane];
  float4 c3 = *(const float4*)&avec[3 * DIN + 4 * lane];
  float v0 = xv.x * c0.x + xv.y * c0.y + xv.z * c0.z + xv.w * c0.w;
  float v1 = xv.x * c1.x + xv.y * c1.y + xv.z * c1.z + xv.w * c1.w;
  float v2 = xv.x * c2.x + xv.y * c2.y + xv.z * c2.z + xv.w * c2.w;
  float v3 = xv.x * c3.x + xv.y * c3.y + xv.z * c3.z + xv.w * c3.w;
#pragma unroll
  for (int o = 1; o < 64; o <<= 1) {
    v0 += __shfl_xor(v0, o); v1 += __shfl_xor(v1, o);
    v2 += __shfl_xor(v2, o); v3 += __shfl_xor(v3, o);
  }
  if (lane == 0) { ss[n] = v0; ss[NN + n] = v1; st[n] = v2; st[NN + n] = v3; }
}

// ---- K_gemm: grid (256, 3). 32-row tiles, one weight-set per block (short blocks, 3/CU).
// Head blocks (y<2) bf16-pack + LDS-transpose their pt2 h-plane directly.
// y==2 writes resid. proj f32 never touches HBM. ----
__global__ __launch_bounds__(256) void k_gemm(const float* __restrict__ x, const float* __restrict__ Wh,
                                              const float* __restrict__ wtr, uint32_t* __restrict__ pt2,
                                              float* __restrict__ resid) {
  const int set = blockIdx.y;
  const float* __restrict__ Wsrc = (set < 2) ? (Wh + set * (DIN * FF)) : wtr;
  const int c = blockIdx.x;            // 32-row chunk
  const int row0 = c * 32;
  __shared__ float xs[32 * 68];        // 8.7 KB
  __shared__ uint16_t pw16[32][132];   // 8.4 KB
  const int tid = threadIdx.x;
  const int ft = tid & 31, rt = tid >> 5;
  const int f0 = ft * 4, r0 = rt * 4;
  float acc[4][4];
#pragma unroll
  for (int j = 0; j < 4; ++j)
#pragma unroll
    for (int k = 0; k < 4; ++k) acc[j][k] = 0.f;

  for (int kc = 0; kc < 4; ++kc) {
    const int d0 = kc * 64;
#pragma unroll
    for (int k2 = 0; k2 < 2; ++k2) {
      int i = tid * 4 + k2 * 1024;
      int r = i >> 6, dd = i & 63;
      *(float4*)&xs[r * 68 + dd] = *(const float4*)&x[(row0 + r) * DIN + d0 + dd];
    }
    __syncthreads();
#pragma unroll
    for (int g = 0; g < 16; ++g) {
      const int dd = g * 4;
      float xr[4][4];
#pragma unroll
      for (int j = 0; j < 4; ++j) {
        float4 t = *(const float4*)&xs[(r0 + j) * 68 + dd];
        xr[j][0] = t.x; xr[j][1] = t.y; xr[j][2] = t.z; xr[j][3] = t.w;
      }
#pragma unroll
      for (int i = 0; i < 4; ++i) {
        float4 w = *(const float4*)&Wsrc[(d0 + dd + i) * FF + f0];
#pragma unroll
        for (int j = 0; j < 4; ++j) {
          float xx = xr[j][i];
          acc[j][0] += xx * w.x; acc[j][1] += xx * w.y;
          acc[j][2] += xx * w.z; acc[j][3] += xx * w.w;
        }
      }
    }
    __syncthreads();
  }

  if (set == 2) {
#pragma unroll
    for (int j = 0; j < 4; ++j)
      *(float4*)&resid[(row0 + r0 + j) * FF + f0] = make_float4(acc[j][0], acc[j][1], acc[j][2], acc[j][3]);
    return;
  }

  // bf16 into LDS [row-in-chunk][f]
#pragma unroll
  for (int j = 0; j < 4; ++j)
#pragma unroll
    for (int k = 0; k < 4; ++k)
      pw16[r0 + j][f0 + k] = bf16c(acc[j][k]);
  __syncthreads();

  // transpose-write this head's pt2 plane: [c][set][f][16 words]
  const int half = tid >> 7, f = tid & 127;
  uint32_t wbuf[8];
#pragma unroll
  for (int i = 0; i < 8; ++i) {
    int p = half * 8 + i;
    wbuf[i] = (uint32_t)pw16[2 * p][f] | ((uint32_t)pw16[2 * p + 1][f] << 16);
  }
  uint32_t* dst = pt2 + ((c * 2 + set) * 128 + f) * 16 + half * 8;
  *(uint4*)&dst[0] = make_uint4(wbuf[0], wbuf[1], wbuf[2], wbuf[3]);
  *(uint4*)&dst[4] = make_uint4(wbuf[4], wbuf[5], wbuf[6], wbuf[7]);
}

// ---- K_csum: colsums from 8 MB bitmask (not the 268 MB mask) + fold ntab.
// Block b owns word-column b (n in [32b,32b+32)). 512 thr: 16 m-slices x 32 n. ----
__global__ __launch_bounds__(512) void k_csum(const uint32_t* __restrict__ bitmask, const float* __restrict__ ss,
                                              const float* __restrict__ st, float4* __restrict__ ntab) {
  __shared__ float red[2][16][32];
  const int t = threadIdx.x;
  const int ns = t & 31, slice = t >> 5;
  const int b = blockIdx.x;
  const int n = 32 * b + ns;
  const float st0 = st[n] * LOG2E, st1 = st[NN + n] * LOG2E;
  float c0 = 0.f, c1 = 0.f;
#pragma unroll 4
  for (int mi = 0; mi < 512; ++mi) {
    const int m = slice * 512 + mi;
    uint32_t bw = bitmask[m * 256 + b];
    bool e = (bw >> ns) & 1u;
    float w0 = exp2fast(lrelu(ss[m] * LOG2E + st0));
    float w1 = exp2fast(lrelu(ss[NN + m] * LOG2E + st1));
    c0 += e ? w0 : 0.f;
    c1 += e ? w1 : 0.f;
  }
  red[0][slice][ns] = c0;
  red[1][slice][ns] = c1;
  __syncthreads();
  if (t < 32) {
    float s0 = 0.f, s1 = 0.f;
#pragma unroll
    for (int k = 0; k < 16; ++k) { s0 += red[0][k][t]; s1 += red[1][k][t]; }
    int nn = 32 * b + t;
    ntab[nn] = make_float4(st[nn] * LOG2E, st[NN + nn] * LOG2E, 1.f / s0, 1.f / s1);
  }
}

// ---- K_vals: DENSE MFMA, SPLIT-K into PRIVATE PARTIALS (unchanged from r3/r4). ----
__global__ __launch_bounds__(256) void k_vals(const uint32_t* __restrict__ bitmask, const uint32_t* __restrict__ pt2,
                                              const float4* __restrict__ ntab, const float* __restrict__ ss,
                                              float* __restrict__ vpart) {
  __shared__ short B2[2][8][4][16][8];   // 16 KB
  __shared__ short A2[2][8][4][16][8];   // 16 KB (128 m-rows)
  const int t = threadIdx.x;
  const int lane = t & 63, wid = t >> 6;
  const int m0 = blockIdx.x * 128;
  const int nc = blockIdx.y;                   // n-chunk: 1024 n
  const int q = lane >> 4, col = lane & 15;
  const int n2 = t & 15, mg = t >> 4;          // A-build: n-pair, m-subgroup(0..15)
  const int fr = t & 127, hB = t >> 7;         // B-stage: f-row, head

  float ssm0[8], ssm1[8];
#pragma unroll
  for (int p = 0; p < 8; ++p) {
    ssm0[p] = ss[m0 + mg + 16 * p] * LOG2E;
    ssm1[p] = ss[NN + m0 + mg + 16 * p] * LOG2E;
  }

  f32x4 acc[2][8];
#pragma unroll
  for (int i = 0; i < 2; ++i)
#pragma unroll
    for (int j = 0; j < 8; ++j) acc[i][j] = (f32x4){0.f, 0.f, 0.f, 0.f};

  uint32_t* B2w = (uint32_t*)&B2[0][0][0][0][0];
  uint32_t* A2w = (uint32_t*)&A2[0][0][0][0][0];

  for (int s = 0; s < 32; ++s) {
    const int n0 = nc * 1024 + s * 32;
    const uint32_t* src = pt2 + (nc * 32 + s) * 4096;   // [h][f][16 words]
    {
      const uint4* p4 = (const uint4*)&src[t * 16];     // h*128+f == t
#pragma unroll
      for (int k = 0; k < 4; ++k) {
        uint4 v = p4[k];
        *(uint4*)&B2w[(((hB * 8 + (fr >> 4)) * 4 + k) * 16 + (fr & 15)) * 4] = v;
      }
    }
    float4 na = ntab[n0 + 2 * n2];
    float4 nb = ntab[n0 + 2 * n2 + 1];
#pragma unroll
    for (int p = 0; p < 8; ++p) {
      const int ml = mg + 16 * p;
      uint32_t bw = bitmask[(size_t)(m0 + ml) * 256 + (n0 >> 5)];
      float e0a = exp2fast(lrelu(ssm0[p] + na.x)) * na.z;
      float e1a = exp2fast(lrelu(ssm1[p] + na.y)) * na.w;
      float e0b = exp2fast(lrelu(ssm0[p] + nb.x)) * nb.z;
      float e1b = exp2fast(lrelu(ssm1[p] + nb.y)) * nb.w;
      bool b0 = (bw >> (2 * n2)) & 1, b1 = (bw >> (2 * n2 + 1)) & 1;
      e0a = b0 ? e0a : 0.f; e1a = b0 ? e1a : 0.f;
      e0b = b1 ? e0b : 0.f; e1b = b1 ? e1b : 0.f;
      int base = (p * 4 + (n2 >> 2)) * 64 + mg * 4 + (n2 & 3);
      A2w[base] = bfpack(e0a, e0b);
      A2w[base + 2048] = bfpack(e1a, e1b);     // h=1 plane
    }
    __syncthreads();
    bf16x8 a00 = *(const bf16x8*)&A2[0][wid * 2][q][col][0];
    bf16x8 a01 = *(const bf16x8*)&A2[0][wid * 2 + 1][q][col][0];
    bf16x8 a10 = *(const bf16x8*)&A2[1][wid * 2][q][col][0];
    bf16x8 a11 = *(const bf16x8*)&A2[1][wid * 2 + 1][q][col][0];
#pragma unroll
    for (int ft = 0; ft < 8; ++ft) {
      bf16x8 b0 = *(const bf16x8*)&B2[0][ft][q][col][0];
      acc[0][ft] = __builtin_amdgcn_mfma_f32_16x16x32_bf16(a00, b0, acc[0][ft], 0, 0, 0);
      acc[1][ft] = __builtin_amdgcn_mfma_f32_16x16x32_bf16(a01, b0, acc[1][ft], 0, 0, 0);
      bf16x8 b1 = *(const bf16x8*)&B2[1][ft][q][col][0];
      acc[0][ft] = __builtin_amdgcn_mfma_f32_16x16x32_bf16(a10, b1, acc[0][ft], 0, 0, 0);
      acc[1][ft] = __builtin_amdgcn_mfma_f32_16x16x32_bf16(a11, b1, acc[1][ft], 0, 0, 0);
    }
    __syncthreads();
  }

  float* dst = vpart + (size_t)nc * NF;
#pragma unroll
  for (int mt2 = 0; mt2 < 2; ++mt2)
#pragma unroll
    for (int ft = 0; ft < 8; ++ft)
#pragma unroll
      for (int r = 0; r < 4; ++r) {
        int mrow = m0 + (wid * 2 + mt2) * 16 + q * 4 + r;
        dst[mrow * FF + ft * 16 + col] = 0.5f * acc[mt2][ft][r];
      }
}

// ---- K_stats: reduce 8 partials -> vals + stats ----
__global__ __launch_bounds__(256) void k_stats(const float* __restrict__ vpart, float* __restrict__ vals,
                                               float* __restrict__ stats) {
  int i = (blockIdx.x * 256 + threadIdx.x) * 4;
  float4 a = make_float4(0.f, 0.f, 0.f, 0.f);
#pragma unroll
  for (int p = 0; p < 8; ++p) {
    float4 v = *(const float4*)&vpart[(size_t)p * NF + i];
    a.x += v.x; a.y += v.y; a.z += v.z; a.w += v.w;
  }
  *(float4*)&vals[i] = a;
  float s = a.x + a.y + a.z + a.w;
  float q = a.x * a.x + a.y * a.y + a.z * a.z + a.w * a.w;
#pragma unroll
  for (int o = 1; o < 64; o <<= 1) { s += __shfl_xor(s, o); q += __shfl_xor(q, o); }
  if ((threadIdx.x & 63) == 0) { atomicAdd(stats, s); atomicAdd(stats + 1, q); }
}

// ---- K_final: instance-norm + residual + ELU ----
__global__ __launch_bounds__(256) void k_final(const float* __restrict__ vals, const float* __restrict__ resid,
                                               const float* __restrict__ stats, float* __restrict__ out) {
  int i = (blockIdx.x * 256 + threadIdx.x) * 4;
  float mu = stats[0] * (1.f / NF);
  float var = stats[1] * (1.f / NF) - mu * mu;
  float rs = rsqrtf(var + EPSI);
  float4 v = *(const float4*)&vals[i];
  float4 r = *(const float4*)&resid[i];
  float t0 = (v.x - mu) * rs + r.x;
  float t1 = (v.y - mu) * rs + r.y;
  float t2 = (v.z - mu) * rs + r.z;
  float t3 = (v.w - mu) * rs + r.w;
  float4 o;
  o.x = t0 > 0.f ? t0 : expm1f(t0);
  o.y = t1 > 0.f ? t1 : expm1f(t1);
  o.z = t2 > 0.f ? t2 : expm1f(t2);
  o.w = t3 > 0.f ? t3 : expm1f(t3);
  *(float4*)&out[i] = o;
}

extern "C" void kernel_launch(void* const* d_in, const int* in_sizes, int n_in,
                              void* d_out, int out_size, void* d_ws, size_t ws_size,
                              hipStream_t stream) {
  const float* x     = (const float*)d_in[0];
  const float* mask  = (const float*)d_in[1];
  const float* W     = (const float*)d_in[2];
  const float* a_src = (const float*)d_in[3];
  const float* a_tgt = (const float*)d_in[4];
  const float* wres  = (const float*)d_in[5];
  float* out = (float*)d_out;
  float* wsf = (float*)d_ws;

  uint32_t* bitmask = (uint32_t*)(wsf + OFF_BM);
  float*    resid   = wsf + OFF_RESID;
  float*    avec    = wsf + OFF_AVEC;
  float*    ss      = wsf + OFF_SS;
  float*    st      = wsf + OFF_ST;
  float*    stats   = wsf + OFF_STATS;
  float4*   ntab    = (float4*)(wsf + OFF_NTAB);
  float*    vals    = wsf + OFF_VALS;
  float*    wt      = wsf + OFF_WT;
  uint32_t* pt2     = (uint32_t*)(wsf + OFF_PT2);
  float*    vpart   = wsf + OFF_VPART;

  (void)hipMemsetAsync(stats, 0, 16 * sizeof(float), stream);

  hipLaunchKernelGGL(k_copy,  dim3(NN / 4),       dim3(256), 0, stream, mask, out + NF, bitmask);
  hipLaunchKernelGGL(k_prep,  dim3(132),          dim3(256), 0, stream, wres, wt, W, a_src, a_tgt, avec);
  hipLaunchKernelGGL(k_ss,    dim3(NN / 4),       dim3(256), 0, stream, x, avec, ss, st);
  hipLaunchKernelGGL(k_gemm,  dim3(NN / 32, 3),   dim3(256), 0, stream, x, W, wt, pt2, resid);
  hipLaunchKernelGGL(k_csum,  dim3(NN / 32),      dim3(512), 0, stream, bitmask, ss, st, ntab);
  hipLaunchKernelGGL(k_vals,  dim3(NN / 128, 8),  dim3(256), 0, stream, bitmask, pt2, ntab, ss, vpart);
  hipLaunchKernelGGL(k_stats, dim3(NF / 1024),    dim3(256), 0, stream, vpart, vals, stats);
  hipLaunchKernelGGL(k_final, dim3(NF / 1024),    dim3(256), 0, stream, vals, resid, stats, out);
}

// Round 7
// 732.905 us; speedup vs baseline: 1.0182x; 1.0182x over previous
//
#include <hip/hip_runtime.h>
#include <stdint.h>

#define NN   8192
#define DIN  256
#define FF   128
#define NF   (NN*FF)          // 1048576
#define SLOPE 0.2f
#define EPSI  1e-5f
#define LOG2E 1.4426950408889634f

typedef short bf16x8 __attribute__((ext_vector_type(8)));
typedef float f32x4 __attribute__((ext_vector_type(4)));
typedef float vf4 __attribute__((ext_vector_type(4)));   // ext-vector float4 (nontemporal-legal)

// ---- workspace layout (float offsets) ----
#define OFF_BM     0                       // bitmask [N][256] u32 (8 MB)
#define OFF_RESID  (2*NF)                  // [N][F] f32
#define OFF_AVEC   (3*NF)                  // [4][DIN] f32: Wa_src(h0,h1), Wa_tgt(h0,h1)
#define OFF_SS     (4*NF)                  // (dead, layout stability)
#define OFF_ST     (OFF_SS + 2*NN)         // s_tgt [2][N], PRE-SCALED by log2e
#define OFF_STAB   (OFF_ST + 2*NN)         // float2[N] = {T0=2^-st0L, T1=2^-st1L}
#define OFF_STATS  (OFF_STAB + 2*NN)       // S, SS (padded to 16)
#define OFF_NTAB   (OFF_STATS + 16)        // float4[N] = {F10*r0, F20*r0, F11*r1, F21*r1}
#define OFF_VALS   (OFF_NTAB + 4*NN)       // [N][F] f32
#define OFF_WT     (OFF_VALS + NF)         // W_res^T [DIN][F]
#define OFF_PT2    (OFF_WT + DIN*FF)       // packedT2: [N/32][2][128][16] u32 (4 MB)
#define OFF_VPART  (OFF_PT2 + NF)          // vpart: [8][N][F] f32 (32 MB)
#define OFF_ETAB   (OFF_VPART + 8*NF)      // float4[N] = {E1h0, E2h0, E1h1, E2h1}

__device__ __forceinline__ float exp2fast(float x) { return __builtin_amdgcn_exp2f(x); }

__device__ __forceinline__ uint32_t bfpack(float a, float b) {
  uint32_t ua = __float_as_uint(a); ua += 0x7fffu + ((ua >> 16) & 1u);
  uint32_t ub = __float_as_uint(b); ub += 0x7fffu + ((ub >> 16) & 1u);
  return (ua >> 16) | (ub & 0xffff0000u);
}
__device__ __forceinline__ uint16_t bf16c(float a) {
  uint32_t u = __float_as_uint(a); u += 0x7fffu + ((u >> 16) & 1u);
  return (uint16_t)(u >> 16);
}

// ---- K_copy: PURE stream. mask -> out copy (vf4) + bitmask emit. 2048 blocks. ----
__global__ __launch_bounds__(256) void k_copy(const float* __restrict__ mask, float* __restrict__ maskout,
                                              uint32_t* __restrict__ bitmask) {
  const int t = threadIdx.x;
  const int L = t & 63, wv = t >> 6;
  const int m0 = blockIdx.x * 4;
#pragma unroll
  for (int j = 0; j < 4; ++j) {
    const size_t rowoff = (size_t)(m0 + j) * NN;
    vf4 v[8];
#pragma unroll
    for (int s = 0; s < 8; ++s)
      v[s] = __builtin_nontemporal_load((const vf4*)&mask[rowoff + s * 1024 + t * 4]);
#pragma unroll
    for (int s = 0; s < 8; ++s) {
      __builtin_nontemporal_store(v[s], (vf4*)&maskout[rowoff + s * 1024 + t * 4]);
      uint32_t nib = (v[s].x > -0.5e9f ? 1u : 0u) | (v[s].y > -0.5e9f ? 2u : 0u) |
                     (v[s].z > -0.5e9f ? 4u : 0u) | (v[s].w > -0.5e9f ? 8u : 0u);
      uint32_t w = nib << (4 * (L & 7));
      w |= __shfl_xor((int)w, 1); w |= __shfl_xor((int)w, 2); w |= __shfl_xor((int)w, 4);
      if ((L & 7) == 0)
        bitmask[(m0 + j) * 256 + s * 32 + wv * 8 + (L >> 3)] = w;
    }
  }
}

// ---- K_prep: W_res transpose (blocks 0..127) + avec (blocks 128..131) ----
__global__ __launch_bounds__(256) void k_prep(const float* __restrict__ wres, float* __restrict__ wtr,
                                              const float* __restrict__ W, const float* __restrict__ a_src,
                                              const float* __restrict__ a_tgt, float* __restrict__ avec) {
  const int b = blockIdx.x;
  if (b < 128) {
    int i = b * 256 + threadIdx.x;
    int d = i >> 7, f = i & 127;
    wtr[i] = wres[f * DIN + d];
  } else {
    int j = b - 128;                       // 0: ss_h0, 1: ss_h1, 2: st_h0, 3: st_h1
    int h = j & 1, tg = j >> 1;
    const float* a = (tg ? a_tgt : a_src) + h * FF;
    const float* Wp = W + ((size_t)h * DIN + threadIdx.x) * FF;
    float s = 0.f;
#pragma unroll 8
    for (int f = 0; f < FF; ++f) s += Wp[f] * a[f];
    avec[j * DIN + threadIdx.x] = s;
  }
}

// ---- K_ss: st (scaled) + per-row exp table E = {2^ssL, 2^(.2 ssL), head1...} ----
__global__ __launch_bounds__(256) void k_ss(const float* __restrict__ x, const float* __restrict__ avec,
                                            float* __restrict__ st, float4* __restrict__ etab) {
  const int lane = threadIdx.x & 63, wid = threadIdx.x >> 6;
  const int n = blockIdx.x * 4 + wid;
  float4 xv = *(const float4*)&x[n * DIN + 4 * lane];
  float4 c0 = *(const float4*)&avec[0 * DIN + 4 * lane];
  float4 c1 = *(const float4*)&avec[1 * DIN + 4 * lane];
  float4 c2 = *(const float4*)&avec[2 * DIN + 4 * lane];
  float4 c3 = *(const float4*)&avec[3 * DIN + 4 * lane];
  float v0 = xv.x * c0.x + xv.y * c0.y + xv.z * c0.z + xv.w * c0.w;
  float v1 = xv.x * c1.x + xv.y * c1.y + xv.z * c1.z + xv.w * c1.w;
  float v2 = xv.x * c2.x + xv.y * c2.y + xv.z * c2.z + xv.w * c2.w;
  float v3 = xv.x * c3.x + xv.y * c3.y + xv.z * c3.z + xv.w * c3.w;
#pragma unroll
  for (int o = 1; o < 64; o <<= 1) {
    v0 += __shfl_xor(v0, o); v1 += __shfl_xor(v1, o);
    v2 += __shfl_xor(v2, o); v3 += __shfl_xor(v3, o);
  }
  if (lane == 0) {
    float s0 = v0 * LOG2E, s1 = v1 * LOG2E;
    st[n] = v2 * LOG2E; st[NN + n] = v3 * LOG2E;
    etab[n] = make_float4(exp2fast(s0), exp2fast(SLOPE * s0),
                          exp2fast(s1), exp2fast(SLOPE * s1));
  }
}

// ---- K_gemm: grid (256, 3). 32-row tiles; heads write pt2 plane direct; y==2 resid. ----
__global__ __launch_bounds__(256) void k_gemm(const float* __restrict__ x, const float* __restrict__ Wh,
                                              const float* __restrict__ wtr, uint32_t* __restrict__ pt2,
                                              float* __restrict__ resid) {
  const int set = blockIdx.y;
  const float* __restrict__ Wsrc = (set < 2) ? (Wh + set * (DIN * FF)) : wtr;
  const int c = blockIdx.x;
  const int row0 = c * 32;
  __shared__ float xs[32 * 68];
  __shared__ uint16_t pw16[32][132];
  const int tid = threadIdx.x;
  const int ft = tid & 31, rt = tid >> 5;
  const int f0 = ft * 4, r0 = rt * 4;
  float acc[4][4];
#pragma unroll
  for (int j = 0; j < 4; ++j)
#pragma unroll
    for (int k = 0; k < 4; ++k) acc[j][k] = 0.f;

  for (int kc = 0; kc < 4; ++kc) {
    const int d0 = kc * 64;
#pragma unroll
    for (int k2 = 0; k2 < 2; ++k2) {
      int i = tid * 4 + k2 * 1024;
      int r = i >> 6, dd = i & 63;
      *(float4*)&xs[r * 68 + dd] = *(const float4*)&x[(row0 + r) * DIN + d0 + dd];
    }
    __syncthreads();
#pragma unroll
    for (int g = 0; g < 16; ++g) {
      const int dd = g * 4;
      float xr[4][4];
#pragma unroll
      for (int j = 0; j < 4; ++j) {
        float4 t = *(const float4*)&xs[(r0 + j) * 68 + dd];
        xr[j][0] = t.x; xr[j][1] = t.y; xr[j][2] = t.z; xr[j][3] = t.w;
      }
#pragma unroll
      for (int i = 0; i < 4; ++i) {
        float4 w = *(const float4*)&Wsrc[(d0 + dd + i) * FF + f0];
#pragma unroll
        for (int j = 0; j < 4; ++j) {
          float xx = xr[j][i];
          acc[j][0] += xx * w.x; acc[j][1] += xx * w.y;
          acc[j][2] += xx * w.z; acc[j][3] += xx * w.w;
        }
      }
    }
    __syncthreads();
  }

  if (set == 2) {
#pragma unroll
    for (int j = 0; j < 4; ++j)
      *(float4*)&resid[(row0 + r0 + j) * FF + f0] = make_float4(acc[j][0], acc[j][1], acc[j][2], acc[j][3]);
    return;
  }

#pragma unroll
  for (int j = 0; j < 4; ++j)
#pragma unroll
    for (int k = 0; k < 4; ++k)
      pw16[r0 + j][f0 + k] = bf16c(acc[j][k]);
  __syncthreads();

  const int half = tid >> 7, f = tid & 127;
  uint32_t wbuf[8];
#pragma unroll
  for (int i = 0; i < 8; ++i) {
    int p = half * 8 + i;
    wbuf[i] = (uint32_t)pw16[2 * p][f] | ((uint32_t)pw16[2 * p + 1][f] << 16);
  }
  uint32_t* dst = pt2 + ((c * 2 + set) * 128 + f) * 16 + half * 8;
  *(uint4*)&dst[0] = make_uint4(wbuf[0], wbuf[1], wbuf[2], wbuf[3]);
  *(uint4*)&dst[4] = make_uint4(wbuf[4], wbuf[5], wbuf[6], wbuf[7]);
}

// ---- K_csum: factored colsums — NO exp in loop. csum = F1*Σ_{y>=0,e}E1 + F2*Σ_{y<0,e}E2.
// Sign test y>=0 <=> E1m >= T (monotone). Emits ntab (F*r folded) + stab (T). ----
__global__ __launch_bounds__(512) void k_csum(const uint32_t* __restrict__ bitmask, const float4* __restrict__ etab,
                                              const float* __restrict__ st, float4* __restrict__ ntab,
                                              float2* __restrict__ stab) {
  __shared__ float red[4][16][32];
  const int t = threadIdx.x;
  const int ns = t & 31, slice = t >> 5;
  const int b = blockIdx.x;
  const int n = 32 * b + ns;
  const float st0 = st[n], st1 = st[NN + n];          // pre-scaled
  const float F10 = exp2fast(st0), F11 = exp2fast(st1);
  const float T0 = __builtin_amdgcn_rcpf(F10), T1 = __builtin_amdgcn_rcpf(F11);
  float aA = 0.f, aB = 0.f, aC = 0.f, aD = 0.f;
#pragma unroll 4
  for (int mi = 0; mi < 512; ++mi) {
    const int m = slice * 512 + mi;
    uint32_t bw = bitmask[m * 256 + b];
    bool e = (bw >> ns) & 1u;
    float4 E = etab[m];
    bool c0 = E.x >= T0, c1 = E.z >= T1;
    aA += (e && c0) ? E.x : 0.f;
    aB += (e && !c0) ? E.y : 0.f;
    aC += (e && c1) ? E.z : 0.f;
    aD += (e && !c1) ? E.w : 0.f;
  }
  red[0][slice][ns] = aA; red[1][slice][ns] = aB;
  red[2][slice][ns] = aC; red[3][slice][ns] = aD;
  __syncthreads();
  if (t < 32) {
    float sA = 0.f, sB = 0.f, sC = 0.f, sD = 0.f;
#pragma unroll
    for (int k = 0; k < 16; ++k) {
      sA += red[0][k][t]; sB += red[1][k][t];
      sC += red[2][k][t]; sD += red[3][k][t];
    }
    const int nn = 32 * b + t;
    const float u0 = st[nn], u1 = st[NN + nn];
    const float G1 = exp2fast(u0), G2 = exp2fast(SLOPE * u0);
    const float H1 = exp2fast(u1), H2 = exp2fast(SLOPE * u1);
    const float r0 = 1.f / (G1 * sA + G2 * sB);
    const float r1 = 1.f / (H1 * sC + H2 * sD);
    ntab[nn] = make_float4(G1 * r0, G2 * r0, H1 * r1, H2 * r1);
    stab[nn] = make_float2(__builtin_amdgcn_rcpf(G1), __builtin_amdgcn_rcpf(H1));
  }
}

// ---- K_vals: DENSE MFMA, split-K private partials. A-build exp-free (E/F select). ----
__global__ __launch_bounds__(256) void k_vals(const uint32_t* __restrict__ bitmask, const uint32_t* __restrict__ pt2,
                                              const float4* __restrict__ ntab, const float2* __restrict__ stab,
                                              const float4* __restrict__ etab, float* __restrict__ vpart) {
  __shared__ short B2[2][8][4][16][8];   // 16 KB
  __shared__ short A2[2][8][4][16][8];   // 16 KB (128 m-rows)
  const int t = threadIdx.x;
  const int lane = t & 63, wid = t >> 6;
  const int m0 = blockIdx.x * 128;
  const int nc = blockIdx.y;                   // n-chunk: 1024 n
  const int q = lane >> 4, col = lane & 15;
  const int n2 = t & 15, mg = t >> 4;          // A-build: n-pair, m-subgroup(0..15)
  const int fr = t & 127, hB = t >> 7;         // B-stage: f-row, head

  float4 E[8];
#pragma unroll
  for (int p = 0; p < 8; ++p) E[p] = etab[m0 + mg + 16 * p];

  f32x4 acc[2][8];
#pragma unroll
  for (int i = 0; i < 2; ++i)
#pragma unroll
    for (int j = 0; j < 8; ++j) acc[i][j] = (f32x4){0.f, 0.f, 0.f, 0.f};

  uint32_t* B2w = (uint32_t*)&B2[0][0][0][0][0];
  uint32_t* A2w = (uint32_t*)&A2[0][0][0][0][0];

  for (int s = 0; s < 32; ++s) {
    const int n0 = nc * 1024 + s * 32;
    const uint32_t* src = pt2 + (nc * 32 + s) * 4096;   // [h][f][16 words]
    {
      const uint4* p4 = (const uint4*)&src[t * 16];     // h*128+f == t
#pragma unroll
      for (int k = 0; k < 4; ++k) {
        uint4 v = p4[k];
        *(uint4*)&B2w[(((hB * 8 + (fr >> 4)) * 4 + k) * 16 + (fr & 15)) * 4] = v;
      }
    }
    float4 na = ntab[n0 + 2 * n2];
    float4 nb = ntab[n0 + 2 * n2 + 1];
    float4 sT = *(const float4*)&stab[n0 + 2 * n2];     // {T0a, T1a, T0b, T1b}
#pragma unroll
    for (int p = 0; p < 8; ++p) {
      const int ml = mg + 16 * p;
      uint32_t bw = bitmask[(size_t)(m0 + ml) * 256 + (n0 >> 5)];
      bool b0 = (bw >> (2 * n2)) & 1, b1 = (bw >> (2 * n2 + 1)) & 1;
      bool ca = E[p].x >= sT.x;
      float w0a = (ca ? E[p].x : E[p].y) * (ca ? na.x : na.y);
      bool da = E[p].z >= sT.y;
      float w1a = (da ? E[p].z : E[p].w) * (da ? na.z : na.w);
      bool cb = E[p].x >= sT.z;
      float w0b = (cb ? E[p].x : E[p].y) * (cb ? nb.x : nb.y);
      bool db = E[p].z >= sT.w;
      float w1b = (db ? E[p].z : E[p].w) * (db ? nb.z : nb.w);
      w0a = b0 ? w0a : 0.f; w1a = b0 ? w1a : 0.f;
      w0b = b1 ? w0b : 0.f; w1b = b1 ? w1b : 0.f;
      int base = (p * 4 + (n2 >> 2)) * 64 + mg * 4 + (n2 & 3);
      A2w[base] = bfpack(w0a, w0b);
      A2w[base + 2048] = bfpack(w1a, w1b);     // h=1 plane
    }
    __syncthreads();
    bf16x8 a00 = *(const bf16x8*)&A2[0][wid * 2][q][col][0];
    bf16x8 a01 = *(const bf16x8*)&A2[0][wid * 2 + 1][q][col][0];
    bf16x8 a10 = *(const bf16x8*)&A2[1][wid * 2][q][col][0];
    bf16x8 a11 = *(const bf16x8*)&A2[1][wid * 2 + 1][q][col][0];
#pragma unroll
    for (int ft = 0; ft < 8; ++ft) {
      bf16x8 b0 = *(const bf16x8*)&B2[0][ft][q][col][0];
      acc[0][ft] = __builtin_amdgcn_mfma_f32_16x16x32_bf16(a00, b0, acc[0][ft], 0, 0, 0);
      acc[1][ft] = __builtin_amdgcn_mfma_f32_16x16x32_bf16(a01, b0, acc[1][ft], 0, 0, 0);
      bf16x8 b1 = *(const bf16x8*)&B2[1][ft][q][col][0];
      acc[0][ft] = __builtin_amdgcn_mfma_f32_16x16x32_bf16(a10, b1, acc[0][ft], 0, 0, 0);
      acc[1][ft] = __builtin_amdgcn_mfma_f32_16x16x32_bf16(a11, b1, acc[1][ft], 0, 0, 0);
    }
    __syncthreads();
  }

  float* dst = vpart + (size_t)nc * NF;
#pragma unroll
  for (int mt2 = 0; mt2 < 2; ++mt2)
#pragma unroll
    for (int ft = 0; ft < 8; ++ft)
#pragma unroll
      for (int r = 0; r < 4; ++r) {
        int mrow = m0 + (wid * 2 + mt2) * 16 + q * 4 + r;
        dst[mrow * FF + ft * 16 + col] = 0.5f * acc[mt2][ft][r];
      }
}

// ---- K_stats: reduce 8 partials -> vals + stats ----
__global__ __launch_bounds__(256) void k_stats(const float* __restrict__ vpart, float* __restrict__ vals,
                                               float* __restrict__ stats) {
  int i = (blockIdx.x * 256 + threadIdx.x) * 4;
  float4 a = make_float4(0.f, 0.f, 0.f, 0.f);
#pragma unroll
  for (int p = 0; p < 8; ++p) {
    float4 v = *(const float4*)&vpart[(size_t)p * NF + i];
    a.x += v.x; a.y += v.y; a.z += v.z; a.w += v.w;
  }
  *(float4*)&vals[i] = a;
  float s = a.x + a.y + a.z + a.w;
  float q = a.x * a.x + a.y * a.y + a.z * a.z + a.w * a.w;
#pragma unroll
  for (int o = 1; o < 64; o <<= 1) { s += __shfl_xor(s, o); q += __shfl_xor(q, o); }
  if ((threadIdx.x & 63) == 0) { atomicAdd(stats, s); atomicAdd(stats + 1, q); }
}

// ---- K_final: instance-norm + residual + ELU ----
__global__ __launch_bounds__(256) void k_final(const float* __restrict__ vals, const float* __restrict__ resid,
                                               const float* __restrict__ stats, float* __restrict__ out) {
  int i = (blockIdx.x * 256 + threadIdx.x) * 4;
  float mu = stats[0] * (1.f / NF);
  float var = stats[1] * (1.f / NF) - mu * mu;
  float rs = rsqrtf(var + EPSI);
  float4 v = *(const float4*)&vals[i];
  float4 r = *(const float4*)&resid[i];
  float t0 = (v.x - mu) * rs + r.x;
  float t1 = (v.y - mu) * rs + r.y;
  float t2 = (v.z - mu) * rs + r.z;
  float t3 = (v.w - mu) * rs + r.w;
  float4 o;
  o.x = t0 > 0.f ? t0 : expm1f(t0);
  o.y = t1 > 0.f ? t1 : expm1f(t1);
  o.z = t2 > 0.f ? t2 : expm1f(t2);
  o.w = t3 > 0.f ? t3 : expm1f(t3);
  *(float4*)&out[i] = o;
}

extern "C" void kernel_launch(void* const* d_in, const int* in_sizes, int n_in,
                              void* d_out, int out_size, void* d_ws, size_t ws_size,
                              hipStream_t stream) {
  const float* x     = (const float*)d_in[0];
  const float* mask  = (const float*)d_in[1];
  const float* W     = (const float*)d_in[2];
  const float* a_src = (const float*)d_in[3];
  const float* a_tgt = (const float*)d_in[4];
  const float* wres  = (const float*)d_in[5];
  float* out = (float*)d_out;
  float* wsf = (float*)d_ws;

  uint32_t* bitmask = (uint32_t*)(wsf + OFF_BM);
  float*    resid   = wsf + OFF_RESID;
  float*    avec    = wsf + OFF_AVEC;
  float*    st      = wsf + OFF_ST;
  float2*   stab    = (float2*)(wsf + OFF_STAB);
  float*    stats   = wsf + OFF_STATS;
  float4*   ntab    = (float4*)(wsf + OFF_NTAB);
  float*    vals    = wsf + OFF_VALS;
  float*    wt      = wsf + OFF_WT;
  uint32_t* pt2     = (uint32_t*)(wsf + OFF_PT2);
  float*    vpart   = wsf + OFF_VPART;
  float4*   etab    = (float4*)(wsf + OFF_ETAB);

  (void)hipMemsetAsync(stats, 0, 16 * sizeof(float), stream);

  hipLaunchKernelGGL(k_copy,  dim3(NN / 4),       dim3(256), 0, stream, mask, out + NF, bitmask);
  hipLaunchKernelGGL(k_prep,  dim3(132),          dim3(256), 0, stream, wres, wt, W, a_src, a_tgt, avec);
  hipLaunchKernelGGL(k_ss,    dim3(NN / 4),       dim3(256), 0, stream, x, avec, st, etab);
  hipLaunchKernelGGL(k_gemm,  dim3(NN / 32, 3),   dim3(256), 0, stream, x, W, wt, pt2, resid);
  hipLaunchKernelGGL(k_csum,  dim3(NN / 32),      dim3(512), 0, stream, bitmask, etab, st, ntab, stab);
  hipLaunchKernelGGL(k_vals,  dim3(NN / 128, 8),  dim3(256), 0, stream, bitmask, pt2, ntab, stab, etab, vpart);
  hipLaunchKernelGGL(k_stats, dim3(NF / 1024),    dim3(256), 0, stream, vpart, vals, stats);
  hipLaunchKernelGGL(k_final, dim3(NF / 1024),    dim3(256), 0, stream, vals, resid, stats, out);
}